// Round 5
// baseline (255.468 us; speedup 1.0000x reference)
//
#include <hip/hip_runtime.h>
#include <hip/hip_bf16.h>
#include <cmath>

#define L 96
#define L3 (L*L*L)
#define NT 4                 // D-tiles per conv block
#define NCONV 864            // 6*24*6 conv workgroups
// B rows padded to 456 shorts (912 B = 57*16B): 16B-aligned rows so the
// whole B matrix DMA-copies linearly; b128 reads at 912B lane-stride are
// bank-uniform (8 lanes per 4-bank slot = minimum for b128).
#define BSTRIDE 456

// conv1 tile: voxel slot padded to 24 shorts (48 B): lane start-bank
// 12*laneV mod 32 covers 8 distinct 4-bank slots -> conflict-free b128.
// TAU48[tau] = ((kd*6+kh)*18 + kw)*24 (short offset)
__device__ __constant__ const int TAU48[27] = {
    0,24,48, 432,456,480, 864,888,912,
    2592,2616,2640, 3024,3048,3072, 3456,3480,3504,
    5184,5208,5232, 5616,5640,5664, 6048,6072,6096};

typedef __attribute__((ext_vector_type(8))) short short8;
typedef __attribute__((ext_vector_type(4))) float floatx4;

__device__ __forceinline__ float eluf(float x) {
    float e = __expf(x) - 1.0f;
    return x > 0.0f ? x : e;
}

__device__ __forceinline__ unsigned short f2bf(float f) {
    __hip_bfloat16 h = __float2bfloat16(f);
    return *reinterpret_cast<unsigned short*>(&h);
}

// wrap into [0,96) for x in [-1, 97)
__device__ __forceinline__ int wrapc(int x) {
    if (x < 0) x += L;
    if (x >= L) x -= L;
    return x;
}

// LDS-visibility barrier WITHOUT the vmcnt(0) drain of __syncthreads:
// global stores / gather loads stay in flight across it.
__device__ __forceinline__ void lgkm_barrier() {
    asm volatile("s_waitcnt lgkmcnt(0)" ::: "memory");
    __builtin_amdgcn_s_barrier();
    __builtin_amdgcn_sched_barrier(0);
}

// ---- weight reorder only: Bmat[N][K], K-stride 456 (448 live + 8 zero pad) ----
__global__ __launch_bounds__(256) void prepw_kernel(
    const float* __restrict__ w1, const float* __restrict__ w2,
    unsigned short* __restrict__ Bm1, unsigned short* __restrict__ Bm2)
{
    int idx = blockIdx.x * 256 + threadIdx.x;
    if (idx < 16*BSTRIDE) {
        int o = idx / BSTRIDE, k = idx % BSTRIDE;
        int tau = k >> 4, i = k & 15;
        float v = (k < 448 && tau < 27 && i < 12) ? w1[tau*192 + i*16 + o] : 0.0f;
        Bm1[idx] = f2bf(v);
    }
    int j = idx - 16*BSTRIDE;
    if (j >= 0 && j < 32*BSTRIDE) {
        int o = j / BSTRIDE, k = j % BSTRIDE;
        int tau = k >> 4;
        int i = k & 15;
        float v = (k < 448 && tau < 27) ? w2[tau*512 + i*32 + o] : 0.0f;
        Bm2[j] = f2bf(v);
    }
}

// ---- fused bonds staging: load spin halo (issue-early) ----
__device__ __forceinline__ void bonds_load(
    const int* __restrict__ lx, int W0, int H0, int D0, int tid,
    int4* sv, int* n1, int* n2, int* n3)
{
    #pragma unroll
    for (int i = 0; i < 3; ++i) {
        int t = tid + i*256;
        if (t < 648) {
            int dd = t / 108, rem = t - dd*108;      // 108 = 6*18
            int hh = rem / 18, ww = rem - hh*18;
            int gd = wrapc(D0 + dd - 1);
            int gh = wrapc(H0 + hh - 1);
            int gw = wrapc(W0 + ww - 1);
            int gdm = (gd == 0) ? L-1 : gd-1;
            int ghm = (gh == 0) ? L-1 : gh-1;
            int gwm = (gw == 0) ? L-1 : gw-1;
            sv[i] = *reinterpret_cast<const int4*>(lx + 4*((gd*L + gh)*L + gw));
            n1[i] = lx[4*((gdm*L + gh)*L + gw) + 1];
            n2[i] = lx[4*((gd*L + ghm)*L + gw) + 2];
            n3[i] = lx[4*((gd*L + gh)*L + gwm) + 3];
        }
    }
}

// ---- fused bonds staging: dot products + ds_write (write-late), 48B slots ----
__device__ __forceinline__ void bonds_write(
    unsigned short* __restrict__ tile, int tid,
    float d00, float d01, float d11,
    const int4* sv, const int* n1, const int* n2, const int* n3)
{
    #pragma unroll
    for (int i = 0; i < 3; ++i) {
        int t = tid + i*256;
        if (t < 648) {
            int s0 = sv[i].x, s1 = sv[i].y, s2 = sv[i].z, s3 = sv[i].w;
            int r1 = n1[i], r2 = n2[i], r3 = n3[i];
            auto dot = [&](int a, int b) -> float {
                return (a == b) ? (a ? d11 : d00) : d01;
            };
            union { unsigned short s[16]; int4 q[2]; } u;
            u.s[0]  = f2bf(dot(s0, s1));
            u.s[1]  = f2bf(dot(s0, s2));
            u.s[2]  = f2bf(dot(s0, s3));
            u.s[3]  = f2bf(dot(s0, r1));
            u.s[4]  = f2bf(dot(s0, r2));
            u.s[5]  = f2bf(dot(s0, r3));
            u.s[6]  = f2bf(dot(s1, s2));
            u.s[7]  = f2bf(dot(s2, s3));
            u.s[8]  = f2bf(dot(s3, s1));
            u.s[9]  = f2bf(dot(r1, r2));
            u.s[10] = f2bf(dot(r2, r3));
            u.s[11] = f2bf(dot(r3, r1));
            u.s[12] = 0; u.s[13] = 0; u.s[14] = 0; u.s[15] = 0;
            int4* dst = reinterpret_cast<int4*>(tile + t*24);
            dst[0] = u.q[0];
            dst[1] = u.q[1];
        }
    }
}

// ---- linear B-matrix DMA: n16 * 456 shorts, 16 B per transfer ----
__device__ __forceinline__ void stage_bmat(
    const unsigned short* __restrict__ Bm, unsigned short* __restrict__ Bls,
    int nxfer, int tid)
{
    #pragma unroll
    for (int i = 0; i < 8; ++i) {
        int t = tid + i*256;
        if (t < nxfer) {
            __builtin_amdgcn_global_load_lds(
                (const __attribute__((address_space(1))) unsigned int*)(Bm + t*8),
                (__attribute__((address_space(3))) unsigned int*)(Bls + t*8),
                16, 0, 0);
        }
    }
}

// XCD-aware bijective swizzle: 864 blocks = 8 XCDs x 108 contiguous tiles.
__device__ __forceinline__ void tile_coords(int& bid, int& W0, int& H0, int& Dz)
{
    bid = (blockIdx.z * 24 + blockIdx.y) * 6 + blockIdx.x;   // 0..863
    int nb = (bid & 7) * 108 + (bid >> 3);                   // bijective (864%8==0)
    W0 = (nb % 6) * 16;
    int t1 = nb / 6;
    H0 = (t1 % 24) * 4;
    Dz = t1 / 24;                                            // 0..5 -> D base Dz*16
}

// ---- conv1: fused bonds + 16ch (12 live) -> 16ch, dbuf overlap, lgkm barriers ----
__global__ __launch_bounds__(256, 2) void conv1_kernel(
    const int* __restrict__ lx, const float* __restrict__ tet,
    const unsigned short* __restrict__ Bm,
    const float* __restrict__ bias, unsigned short* __restrict__ y)
{
    __shared__ __attribute__((aligned(16))) unsigned short tile[2][6*6*18*24]; // 2x31104 B
    __shared__ __attribute__((aligned(16))) unsigned short Bls[16*BSTRIDE];    // 14592 B
    int tid = threadIdx.x;
    int bid, W0, H0, Dz;
    tile_coords(bid, W0, H0, Dz);

    float t00 = tet[0], t01 = tet[1], t10 = tet[2], t11 = tet[3];
    float d00 = t00*t00 + t01*t01;
    float d01 = t00*t10 + t01*t11;
    float d11 = t10*t10 + t11*t11;

    stage_bmat(Bm, Bls, 912, tid);              // once per block (amortized 4x)

    int4 sv[3]; int n1[3], n2[3], n3[3];
    bonds_load(lx, W0, H0, Dz*16, tid, sv, n1, n2, n3);
    bonds_write(tile[0], tid, d00, d01, d11, sv, n1, n2, n3);
    __syncthreads();                            // full drain once: bmat DMA + LDS

    int lane = tid & 63, wave = tid >> 6;
    int laneV = lane & 15, g = lane >> 4;
    int gb = g >> 1;
    int abase = laneV*24 + (g & 1)*8;

    // swapped MFMA: D[out_ch][vox] -> lane holds ch g*4+r of voxel laneV
    float bch[4];
    #pragma unroll
    for (int r = 0; r < 4; ++r) bch[r] = bias[g*4 + r];

    int moff[4];
    #pragma unroll
    for (int m = 0; m < 4; ++m) {
        int mt = wave*4 + m;                      // dd = mt>>2, hh = mt&3
        moff[m] = ((mt >> 2)*6 + (mt & 3))*432;   // row stride 18*24
    }

    for (int t = 0; t < NT; ++t) {
        // issue next tile's spin gather; latency hides under this tile's MFMAs
        if (t < NT-1)
            bonds_load(lx, W0, H0, Dz*16 + 4*(t+1), tid, sv, n1, n2, n3);

        const unsigned short* tl = tile[t & 1];

        floatx4 acc[4];
        #pragma unroll
        for (int m = 0; m < 4; ++m) acc[m] = (floatx4)(0.0f);

        short8 aC[4], aN[4], bC, bN;
        {
            int a0 = abase + (gb ? TAU48[1] : TAU48[0]);
            bC = *reinterpret_cast<const short8*>(&Bls[laneV*BSTRIDE + g*8]);
            #pragma unroll
            for (int m = 0; m < 4; ++m)
                aC[m] = *reinterpret_cast<const short8*>(&tl[moff[m] + a0]);
        }

        #pragma unroll
        for (int kt = 0; kt < 14; ++kt) {
            if (kt < 13) {
                int tev = TAU48[2*(kt+1)];
                int tod = TAU48[(2*(kt+1)+1 > 26) ? 26 : 2*(kt+1)+1];
                int an = abase + (gb ? tod : tev);
                bN = *reinterpret_cast<const short8*>(&Bls[laneV*BSTRIDE + (kt+1)*32 + g*8]);
                #pragma unroll
                for (int m = 0; m < 4; ++m)
                    aN[m] = *reinterpret_cast<const short8*>(&tl[moff[m] + an]);
            }
            #pragma unroll
            for (int m = 0; m < 4; ++m)
                acc[m] = __builtin_amdgcn_mfma_f32_16x16x32_bf16(bC, aC[m], acc[m], 0, 0, 0);
            if (kt < 13) {
                #pragma unroll
                for (int m = 0; m < 4; ++m) aC[m] = aN[m];
                bC = bN;
            }
        }

        // convert + ds_write next tile into the other buffer
        if (t < NT-1)
            bonds_write(tile[(t+1) & 1], tid, d00, d01, d11, sv, n1, n2, n3);

        int D0 = Dz*16 + t*4;
        #pragma unroll
        for (int m = 0; m < 4; ++m) {
            int mt = wave*4 + m;
            int d = D0 + (mt >> 2), h = H0 + (mt & 3);
            int w = W0 + laneV;
            union { unsigned short s[4]; uint2 v; } o;
            #pragma unroll
            for (int r = 0; r < 4; ++r)
                o.s[r] = f2bf(eluf(acc[m][r] + bch[r]));
            *reinterpret_cast<uint2*>(&y[((size_t)((d*L + h)*L + w))*16 + g*4]) = o.v;
        }

        if (t < NT-1)
            lgkm_barrier();   // LDS visibility only; stores/gathers stay in flight
    }
}

// ---- conv2: 16 -> 32, A streamed straight from L2 (y1 is L2-resident),
// ---- B in LDS, NO per-tile barriers, 4 blocks/CU, fused reduce ----
__global__ __launch_bounds__(256, 4) void conv2_kernel(
    const unsigned short* __restrict__ x, const unsigned short* __restrict__ Bm,
    const float* __restrict__ bias, const float* __restrict__ wd,
    float* __restrict__ partials)
{
    __shared__ __attribute__((aligned(16))) unsigned short Bls[32*BSTRIDE]; // 29184 B
    __shared__ float red[4];
    int tid = threadIdx.x;
    int bid, W0, H0, Dz;
    tile_coords(bid, W0, H0, Dz);

    stage_bmat(Bm, Bls, 1824, tid);             // once per block
    __syncthreads();                            // B ready (single full drain)

    int lane = tid & 63, wave = tid >> 6;
    int laneV = lane & 15, g = lane >> 4;
    int gb = g >> 1;
    float b2a = bias[laneV], b2b = bias[16 + laneV];
    float wda = wd[laneV],  wdb = wd[16 + laneV];

    // per-lane W short-offsets for kw=0,1,2 (wrapped) incl channel half
    int wb0 = wrapc(W0 + laneV - 1)*16 + (g & 1)*8;
    int wb1 = wrapc(W0 + laneV    )*16 + (g & 1)*8;
    int wb2 = wrapc(W0 + laneV + 1)*16 + (g & 1)*8;

    float s = 0.0f;

    for (int t = 0; t < NT; ++t) {
        int D0 = Dz*16 + t*4;
        int dbase = D0 + wave - 1;               // wave-uniform d anchor

        floatx4 acc[4][2];
        #pragma unroll
        for (int m = 0; m < 4; ++m) {
            acc[m][0] = (floatx4)(0.0f);
            acc[m][1] = (floatx4)(0.0f);
        }

        short8 aC[4], aN[4], bC0, bC1, bN0, bN1;

        // A-fragment loader for tap pair (te for gb=0 lanes, to for gb=1)
        auto loadA = [&](int te, int to, short8* dst) {
            int kd = gb ? (to/9)     : (te/9);
            int kh = gb ? ((to/3)%3) : ((te/3)%3);
            int kwo, kwe = te % 3;  kwo = to % 3;
            int wsel = gb ? (kwo==0 ? wb0 : (kwo==1 ? wb1 : wb2))
                          : (kwe==0 ? wb0 : (kwe==1 ? wb1 : wb2));
            int d = wrapc(dbase + kd);
            #pragma unroll
            for (int m = 0; m < 4; ++m) {
                int h = wrapc(H0 + m - 1 + kh);
                dst[m] = *reinterpret_cast<const short8*>(&x[(size_t)((d*L + h)*L)*16 + wsel]);
            }
        };

        loadA(0, 1, aC);
        bC0 = *reinterpret_cast<const short8*>(&Bls[laneV*BSTRIDE + g*8]);
        bC1 = *reinterpret_cast<const short8*>(&Bls[(16 + laneV)*BSTRIDE + g*8]);

        #pragma unroll
        for (int kt = 0; kt < 14; ++kt) {
            if (kt < 13) {
                int te = 2*(kt+1);
                int to = (te+1 > 26) ? 26 : te+1;
                loadA(te, to, aN);
                bN0 = *reinterpret_cast<const short8*>(&Bls[laneV*BSTRIDE + (kt+1)*32 + g*8]);
                bN1 = *reinterpret_cast<const short8*>(&Bls[(16 + laneV)*BSTRIDE + (kt+1)*32 + g*8]);
            }
            #pragma unroll
            for (int m = 0; m < 4; ++m) {
                acc[m][0] = __builtin_amdgcn_mfma_f32_16x16x32_bf16(aC[m], bC0, acc[m][0], 0, 0, 0);
                acc[m][1] = __builtin_amdgcn_mfma_f32_16x16x32_bf16(aC[m], bC1, acc[m][1], 0, 0, 0);
            }
            if (kt < 13) {
                #pragma unroll
                for (int m = 0; m < 4; ++m) aC[m] = aN[m];
                bC0 = bN0; bC1 = bN1;
            }
        }

        #pragma unroll
        for (int m = 0; m < 4; ++m) {
            #pragma unroll
            for (int reg = 0; reg < 4; ++reg) {
                s += eluf(acc[m][0][reg] + b2a) * wda;
                s += eluf(acc[m][1][reg] + b2b) * wdb;
            }
        }
    }

    #pragma unroll
    for (int off = 32; off; off >>= 1) s += __shfl_down(s, off);
    if (lane == 0) red[wave] = s;
    __syncthreads();
    if (tid == 0) {
        partials[bid] = red[0] + red[1] + red[2] + red[3];
    }
}

// ---- final reduce ----
__global__ __launch_bounds__(256) void final_kernel(
    const float* __restrict__ partials, float* __restrict__ out)
{
    float s = 0.0f;
    for (int i = threadIdx.x; i < NCONV; i += 256) s += partials[i];
    #pragma unroll
    for (int off = 32; off; off >>= 1) s += __shfl_down(s, off);
    __shared__ float red[4];
    int lane = threadIdx.x & 63;
    int wv   = threadIdx.x >> 6;
    if (lane == 0) red[wv] = s;
    __syncthreads();
    if (threadIdx.x == 0)
        out[0] = (red[0] + red[1] + red[2] + red[3]) * (1.0f / (float)L3);
}

extern "C" void kernel_launch(void* const* d_in, const int* in_sizes, int n_in,
                              void* d_out, int out_size, void* d_ws, size_t ws_size,
                              hipStream_t stream) {
    const int*   lx  = (const int*)  d_in[0];
    const float* tet = (const float*)d_in[1];
    const float* w1  = (const float*)d_in[2];
    const float* b1  = (const float*)d_in[3];
    const float* w2  = (const float*)d_in[4];
    const float* b2  = (const float*)d_in[5];
    const float* wd  = (const float*)d_in[6];
    float* out = (float*)d_out;

    char* ws = (char*)d_ws;
    const size_t ARR_BYTES = (size_t)L3 * 16 * 2;           // 28.3 MB
    unsigned short* y1   = (unsigned short*)ws;
    unsigned short* Bm1  = (unsigned short*)(ws + ARR_BYTES);
    unsigned short* Bm2  = (unsigned short*)(ws + ARR_BYTES + 16*BSTRIDE*2);
    float* partials      = (float*)         (ws + ARR_BYTES + 48*BSTRIDE*2);

    prepw_kernel<<<86, 256, 0, stream>>>(w1, w2, Bm1, Bm2);
    conv1_kernel<<<dim3(6,24,6), 256, 0, stream>>>(lx, tet, Bm1, b1, y1);
    conv2_kernel<<<dim3(6,24,6), 256, 0, stream>>>(y1, Bm2, b2, wd, partials);
    final_kernel<<<1, 256, 0, stream>>>(partials, out);
}

// Round 6
// 182.273 us; speedup vs baseline: 1.4016x; 1.4016x over previous
//
#include <hip/hip_runtime.h>
#include <hip/hip_bf16.h>
#include <cmath>

#define L 96
#define L3 (L*L*L)
#define NT 4                 // D-tiles per conv block
#define NCONV 864            // 6*24*6 conv workgroups
#define BSTRIDE 456          // B rows padded to 456 shorts (912 B)
#define VSLOT 24             // shorts per voxel slot (48 B) -> conflict-free b128
#define ROWSTRIDE 432        // 18*VSLOT shorts per (dd,hh) row

// tap -> tile short-offset: TAU48[tau] = ((kd*6+kh)*18 + kw)*VSLOT
__device__ __constant__ const int TAU48[27] = {
    0,24,48, 432,456,480, 864,888,912,
    2592,2616,2640, 3024,3048,3072, 3456,3480,3504,
    5184,5208,5232, 5616,5640,5664, 6048,6072,6096};

typedef __attribute__((ext_vector_type(8))) short short8;
typedef __attribute__((ext_vector_type(4))) float floatx4;

__device__ __forceinline__ float eluf(float x) {
    float e = __expf(x) - 1.0f;
    return x > 0.0f ? x : e;
}

__device__ __forceinline__ unsigned short f2bf(float f) {
    __hip_bfloat16 h = __float2bfloat16(f);
    return *reinterpret_cast<unsigned short*>(&h);
}

// wrap into [0,96) for x in [-1, 97)
__device__ __forceinline__ int wrapc(int x) {
    if (x < 0) x += L;
    if (x >= L) x -= L;
    return x;
}

// LDS-visibility barrier WITHOUT the vmcnt(0) drain: global stores/gathers
// stay in flight across it.
__device__ __forceinline__ void lgkm_barrier() {
    asm volatile("s_waitcnt lgkmcnt(0)" ::: "memory");
    __builtin_amdgcn_s_barrier();
    __builtin_amdgcn_sched_barrier(0);
}

// barrier that also waits for outstanding global_load_lds DMA (tile swap)
__device__ __forceinline__ void vm_barrier() {
    asm volatile("s_waitcnt vmcnt(0) lgkmcnt(0)" ::: "memory");
    __builtin_amdgcn_s_barrier();
    __builtin_amdgcn_sched_barrier(0);
}

// ---- weight reorder only: Bmat[N][K], K-stride 456 (448 live + 8 zero pad) ----
__global__ __launch_bounds__(256) void prepw_kernel(
    const float* __restrict__ w1, const float* __restrict__ w2,
    unsigned short* __restrict__ Bm1, unsigned short* __restrict__ Bm2)
{
    int idx = blockIdx.x * 256 + threadIdx.x;
    if (idx < 16*BSTRIDE) {
        int o = idx / BSTRIDE, k = idx % BSTRIDE;
        int tau = k >> 4, i = k & 15;
        float v = (k < 448 && tau < 27 && i < 12) ? w1[tau*192 + i*16 + o] : 0.0f;
        Bm1[idx] = f2bf(v);
    }
    int j = idx - 16*BSTRIDE;
    if (j >= 0 && j < 32*BSTRIDE) {
        int o = j / BSTRIDE, k = j % BSTRIDE;
        int tau = k >> 4;
        int i = k & 15;
        float v = (k < 448 && tau < 27) ? w2[tau*512 + i*32 + o] : 0.0f;
        Bm2[j] = f2bf(v);
    }
}

// ---- fused bonds staging: load spin halo (issue-early) ----
__device__ __forceinline__ void bonds_load(
    const int* __restrict__ lx, int W0, int H0, int D0, int tid,
    int4* sv, int* n1, int* n2, int* n3)
{
    #pragma unroll
    for (int i = 0; i < 3; ++i) {
        int t = tid + i*256;
        if (t < 648) {
            int dd = t / 108, rem = t - dd*108;      // 108 = 6*18
            int hh = rem / 18, ww = rem - hh*18;
            int gd = wrapc(D0 + dd - 1);
            int gh = wrapc(H0 + hh - 1);
            int gw = wrapc(W0 + ww - 1);
            int gdm = (gd == 0) ? L-1 : gd-1;
            int ghm = (gh == 0) ? L-1 : gh-1;
            int gwm = (gw == 0) ? L-1 : gw-1;
            sv[i] = *reinterpret_cast<const int4*>(lx + 4*((gd*L + gh)*L + gw));
            n1[i] = lx[4*((gdm*L + gh)*L + gw) + 1];
            n2[i] = lx[4*((gd*L + ghm)*L + gw) + 2];
            n3[i] = lx[4*((gd*L + gh)*L + gwm) + 3];
        }
    }
}

// ---- fused bonds staging: dot products + ds_write (write-late), 48B slots ----
__device__ __forceinline__ void bonds_write(
    unsigned short* __restrict__ tile, int tid,
    float d00, float d01, float d11,
    const int4* sv, const int* n1, const int* n2, const int* n3)
{
    #pragma unroll
    for (int i = 0; i < 3; ++i) {
        int t = tid + i*256;
        if (t < 648) {
            int s0 = sv[i].x, s1 = sv[i].y, s2 = sv[i].z, s3 = sv[i].w;
            int r1 = n1[i], r2 = n2[i], r3 = n3[i];
            auto dot = [&](int a, int b) -> float {
                return (a == b) ? (a ? d11 : d00) : d01;
            };
            union { unsigned short s[16]; int4 q[2]; } u;
            u.s[0]  = f2bf(dot(s0, s1));
            u.s[1]  = f2bf(dot(s0, s2));
            u.s[2]  = f2bf(dot(s0, s3));
            u.s[3]  = f2bf(dot(s0, r1));
            u.s[4]  = f2bf(dot(s0, r2));
            u.s[5]  = f2bf(dot(s0, r3));
            u.s[6]  = f2bf(dot(s1, s2));
            u.s[7]  = f2bf(dot(s2, s3));
            u.s[8]  = f2bf(dot(s3, s1));
            u.s[9]  = f2bf(dot(r1, r2));
            u.s[10] = f2bf(dot(r2, r3));
            u.s[11] = f2bf(dot(r3, r1));
            u.s[12] = 0; u.s[13] = 0; u.s[14] = 0; u.s[15] = 0;
            int4* dst = reinterpret_cast<int4*>(tile + t*VSLOT);
            dst[0] = u.q[0];
            dst[1] = u.q[1];
        }
    }
}

// ---- stage 6x6x18 PADDED tile (y1 is stored with 24-short voxel slots,
// ---- so a LINEAR global_load_lds copy lands the padded layout for free) ----
__device__ __forceinline__ void stage_tile24(
    const unsigned short* __restrict__ x, unsigned short* __restrict__ tile,
    int W0, int H0, int D0, int tid)
{
    #pragma unroll
    for (int i = 0; i < 8; ++i) {
        int t = tid + i*256;                     // 1944 granules of 16 B
        if (i < 7 || t < 1944) {
            int v = t / 3, p = t - v*3;          // voxel, 16B-part
            int r = v / 18, ww = v - r*18;       // r = dd*6+hh
            int dd = r / 6, hh = r - dd*6;
            int gd = wrapc(D0 + dd - 1);
            int gh = wrapc(H0 + hh - 1);
            int gw = wrapc(W0 + ww - 1);
            size_t gi = ((size_t)((gd*L + gh)*L + gw))*VSLOT + p*8;
            __builtin_amdgcn_global_load_lds(
                (const __attribute__((address_space(1))) unsigned int*)(x + gi),
                (__attribute__((address_space(3))) unsigned int*)(tile + t*8),
                16, 0, 0);
        }
    }
}

// XCD-aware bijective swizzle: 864 blocks = 8 XCDs x 108 contiguous tiles.
__device__ __forceinline__ void tile_coords(int& bid, int& W0, int& H0, int& Dz)
{
    bid = (blockIdx.z * 24 + blockIdx.y) * 6 + blockIdx.x;   // 0..863
    int nb = (bid & 7) * 108 + (bid >> 3);                   // bijective (864%8==0)
    W0 = (nb % 6) * 16;
    int t1 = nb / 6;
    H0 = (t1 % 24) * 4;
    Dz = t1 / 24;                                            // 0..5 -> D base Dz*16
}

// ---- conv1: fused bonds + 16ch (12 live) -> 16ch, B in regs, dbuf overlap ----
__global__ __launch_bounds__(256, 2) void conv1_kernel(
    const int* __restrict__ lx, const float* __restrict__ tet,
    const unsigned short* __restrict__ Bm,
    const float* __restrict__ bias, unsigned short* __restrict__ y)
{
    __shared__ __attribute__((aligned(16))) unsigned short tile[2][6*6*18*VSLOT]; // 2x31104 B
    int tid = threadIdx.x;
    int bid, W0, H0, Dz;
    tile_coords(bid, W0, H0, Dz);

    int lane = tid & 63, wave = tid >> 6;
    int laneV = lane & 15, g = lane >> 4;
    int gb = g >> 1;
    int abase = laneV*VSLOT + (g & 1)*8;

    float t00 = tet[0], t01 = tet[1], t10 = tet[2], t11 = tet[3];
    float d00 = t00*t00 + t01*t01;
    float d01 = t00*t10 + t01*t11;
    float d11 = t10*t10 + t11*t11;

    // B in registers: lane's row = out-ch laneV, k-slice g*8 (wave-invariant)
    short8 bR[14];
    #pragma unroll
    for (int kt = 0; kt < 14; ++kt)
        bR[kt] = *reinterpret_cast<const short8*>(&Bm[laneV*BSTRIDE + kt*32 + g*8]);

    int4 sv[3]; int n1[3], n2[3], n3[3];
    bonds_load(lx, W0, H0, Dz*16, tid, sv, n1, n2, n3);
    bonds_write(tile[0], tid, d00, d01, d11, sv, n1, n2, n3);
    __syncthreads();

    // swapped MFMA: D[out_ch][vox] -> lane holds ch g*4+r of voxel laneV
    float bch[4];
    #pragma unroll
    for (int r = 0; r < 4; ++r) bch[r] = bias[g*4 + r];

    int moff[4];
    #pragma unroll
    for (int m = 0; m < 4; ++m) {
        int mt = wave*4 + m;                      // dd = mt>>2, hh = mt&3
        moff[m] = ((mt >> 2)*6 + (mt & 3))*ROWSTRIDE;
    }

    for (int t = 0; t < NT; ++t) {
        // issue next tile's spin gather; latency hides under this tile's MFMAs
        if (t < NT-1)
            bonds_load(lx, W0, H0, Dz*16 + 4*(t+1), tid, sv, n1, n2, n3);

        const unsigned short* tl = tile[t & 1];

        floatx4 acc[4];
        #pragma unroll
        for (int m = 0; m < 4; ++m) acc[m] = (floatx4)(0.0f);

        #pragma unroll
        for (int kt = 0; kt < 14; ++kt) {
            int te = TAU48[2*kt];
            int to = TAU48[(2*kt+1 > 26) ? 26 : 2*kt+1];
            int an = abase + (gb ? to : te);
            short8 a[4];
            #pragma unroll
            for (int m = 0; m < 4; ++m)
                a[m] = *reinterpret_cast<const short8*>(&tl[moff[m] + an]);
            #pragma unroll
            for (int m = 0; m < 4; ++m)
                acc[m] = __builtin_amdgcn_mfma_f32_16x16x32_bf16(bR[kt], a[m], acc[m], 0, 0, 0);
        }

        // convert + ds_write next tile into the other buffer
        if (t < NT-1)
            bonds_write(tile[(t+1) & 1], tid, d00, d01, d11, sv, n1, n2, n3);

        int D0 = Dz*16 + t*4;
        #pragma unroll
        for (int m = 0; m < 4; ++m) {
            int mt = wave*4 + m;
            int d = D0 + (mt >> 2), h = H0 + (mt & 3);
            int w = W0 + laneV;
            union { unsigned short s[4]; uint2 v; } o;
            #pragma unroll
            for (int r = 0; r < 4; ++r)
                o.s[r] = f2bf(eluf(acc[m][r] + bch[r]));
            *reinterpret_cast<uint2*>(&y[((size_t)((d*L + h)*L + w))*VSLOT + g*4]) = o.v;
        }

        if (t < NT-1)
            lgkm_barrier();   // LDS visibility only; stores/gathers stay in flight
    }
}

// ---- conv2: 16 -> 32, padded dbuf LDS staging, B in regs, fused reduce ----
__global__ __launch_bounds__(256, 2) void conv2_kernel(
    const unsigned short* __restrict__ x, const unsigned short* __restrict__ Bm,
    const float* __restrict__ bias, const float* __restrict__ wd,
    float* __restrict__ partials)
{
    __shared__ __attribute__((aligned(16))) unsigned short tile[2][6*6*18*VSLOT]; // 2x31104 B
    __shared__ float red[4];
    int tid = threadIdx.x;
    int bid, W0, H0, Dz;
    tile_coords(bid, W0, H0, Dz);

    int lane = tid & 63, wave = tid >> 6;
    int laneV = lane & 15, g = lane >> 4;
    int gb = g >> 1;
    int abase = laneV*VSLOT + (g & 1)*8;

    stage_tile24(x, tile[0], W0, H0, Dz*16, tid);

    // B in registers: rows laneV and 16+laneV (wave-invariant pattern)
    short8 bR0[14], bR1[14];
    #pragma unroll
    for (int kt = 0; kt < 14; ++kt) {
        bR0[kt] = *reinterpret_cast<const short8*>(&Bm[laneV*BSTRIDE + kt*32 + g*8]);
        bR1[kt] = *reinterpret_cast<const short8*>(&Bm[(16 + laneV)*BSTRIDE + kt*32 + g*8]);
    }

    float b2a = bias[laneV], b2b = bias[16 + laneV];
    float wda = wd[laneV],  wdb = wd[16 + laneV];

    int moff[4];
    #pragma unroll
    for (int m = 0; m < 4; ++m) {
        int mt = wave*4 + m;
        moff[m] = ((mt >> 2)*6 + (mt & 3))*ROWSTRIDE;
    }

    __syncthreads();   // tile0 DMA + B reg loads complete

    float s = 0.0f;

    for (int t = 0; t < NT; ++t) {
        if (t < NT-1)
            stage_tile24(x, tile[(t+1) & 1], W0, H0, Dz*16 + 4*(t+1), tid);

        const unsigned short* tl = tile[t & 1];

        floatx4 acc[4][2];
        #pragma unroll
        for (int m = 0; m < 4; ++m) {
            acc[m][0] = (floatx4)(0.0f);
            acc[m][1] = (floatx4)(0.0f);
        }

        #pragma unroll
        for (int kt = 0; kt < 14; ++kt) {
            int te = TAU48[2*kt];
            int to = TAU48[(2*kt+1 > 26) ? 26 : 2*kt+1];
            int an = abase + (gb ? to : te);
            short8 a[4];
            #pragma unroll
            for (int m = 0; m < 4; ++m)
                a[m] = *reinterpret_cast<const short8*>(&tl[moff[m] + an]);
            #pragma unroll
            for (int m = 0; m < 4; ++m) {
                acc[m][0] = __builtin_amdgcn_mfma_f32_16x16x32_bf16(a[m], bR0[kt], acc[m][0], 0, 0, 0);
                acc[m][1] = __builtin_amdgcn_mfma_f32_16x16x32_bf16(a[m], bR1[kt], acc[m][1], 0, 0, 0);
            }
        }

        #pragma unroll
        for (int m = 0; m < 4; ++m) {
            #pragma unroll
            for (int reg = 0; reg < 4; ++reg) {
                s += eluf(acc[m][0][reg] + b2a) * wda;
                s += eluf(acc[m][1][reg] + b2b) * wdb;
            }
        }

        if (t < NT-1)
            vm_barrier();    // next tile DMA complete + all reads of cur done
    }

    #pragma unroll
    for (int off = 32; off; off >>= 1) s += __shfl_down(s, off);
    if (lane == 0) red[wave] = s;
    __syncthreads();
    if (tid == 0) {
        partials[bid] = red[0] + red[1] + red[2] + red[3];
    }
}

// ---- final reduce ----
__global__ __launch_bounds__(256) void final_kernel(
    const float* __restrict__ partials, float* __restrict__ out)
{
    float s = 0.0f;
    for (int i = threadIdx.x; i < NCONV; i += 256) s += partials[i];
    #pragma unroll
    for (int off = 32; off; off >>= 1) s += __shfl_down(s, off);
    __shared__ float red[4];
    int lane = threadIdx.x & 63;
    int wv   = threadIdx.x >> 6;
    if (lane == 0) red[wv] = s;
    __syncthreads();
    if (threadIdx.x == 0)
        out[0] = (red[0] + red[1] + red[2] + red[3]) * (1.0f / (float)L3);
}

extern "C" void kernel_launch(void* const* d_in, const int* in_sizes, int n_in,
                              void* d_out, int out_size, void* d_ws, size_t ws_size,
                              hipStream_t stream) {
    const int*   lx  = (const int*)  d_in[0];
    const float* tet = (const float*)d_in[1];
    const float* w1  = (const float*)d_in[2];
    const float* b1  = (const float*)d_in[3];
    const float* w2  = (const float*)d_in[4];
    const float* b2  = (const float*)d_in[5];
    const float* wd  = (const float*)d_in[6];
    float* out = (float*)d_out;

    char* ws = (char*)d_ws;
    const size_t Y1_BYTES = (size_t)L3 * VSLOT * 2;          // 42.5 MB padded
    unsigned short* y1   = (unsigned short*)ws;
    unsigned short* Bm1  = (unsigned short*)(ws + Y1_BYTES);
    unsigned short* Bm2  = (unsigned short*)(ws + Y1_BYTES + 16*BSTRIDE*2);
    float* partials      = (float*)         (ws + Y1_BYTES + 48*BSTRIDE*2);

    prepw_kernel<<<86, 256, 0, stream>>>(w1, w2, Bm1, Bm2);
    conv1_kernel<<<dim3(6,24,6), 256, 0, stream>>>(lx, tet, Bm1, b1, y1);
    conv2_kernel<<<dim3(6,24,6), 256, 0, stream>>>(y1, Bm2, b2, wd, partials);
    final_kernel<<<1, 256, 0, stream>>>(partials, out);
}

// Round 7
// 167.090 us; speedup vs baseline: 1.5289x; 1.0909x over previous
//
#include <hip/hip_runtime.h>
#include <hip/hip_bf16.h>
#include <cmath>

#define L 96
#define L3 (L*L*L)
#define NT 4                 // D-tiles per conv block
#define NCONV 864            // 6*24*6 conv workgroups
#define BSTRIDE 456          // B rows padded to 456 shorts (912 B)
#define VSLOT 24             // shorts per voxel slot (48 B)
#define ROWSTRIDE 432        // 18*VSLOT shorts per (dd,hh) row

// tap -> tile short-offset: TAU48[tau] = ((kd*6+kh)*18 + kw)*VSLOT
__device__ __constant__ const int TAU48[27] = {
    0,24,48, 432,456,480, 864,888,912,
    2592,2616,2640, 3024,3048,3072, 3456,3480,3504,
    5184,5208,5232, 5616,5640,5664, 6048,6072,6096};

typedef __attribute__((ext_vector_type(8))) short short8;
typedef __attribute__((ext_vector_type(4))) float floatx4;

__device__ __forceinline__ float eluf(float x) {
    float e = __expf(x) - 1.0f;
    return x > 0.0f ? x : e;
}

__device__ __forceinline__ unsigned short f2bf(float f) {
    __hip_bfloat16 h = __float2bfloat16(f);
    return *reinterpret_cast<unsigned short*>(&h);
}

// wrap into [0,96) for x in [-1, 97)
__device__ __forceinline__ int wrapc(int x) {
    if (x < 0) x += L;
    if (x >= L) x -= L;
    return x;
}

// LDS-visibility barrier WITHOUT the vmcnt(0) drain: global stores/gathers
// stay in flight across it.
__device__ __forceinline__ void lgkm_barrier() {
    asm volatile("s_waitcnt lgkmcnt(0)" ::: "memory");
    __builtin_amdgcn_s_barrier();
    __builtin_amdgcn_sched_barrier(0);
}

// barrier that also waits for outstanding global_load_lds DMA (tile swap)
__device__ __forceinline__ void vm_barrier() {
    asm volatile("s_waitcnt vmcnt(0) lgkmcnt(0)" ::: "memory");
    __builtin_amdgcn_s_barrier();
    __builtin_amdgcn_sched_barrier(0);
}

// ---- weight reorder only: Bmat[N][K], K-stride 456 (448 live + 8 zero pad) ----
__global__ __launch_bounds__(256) void prepw_kernel(
    const float* __restrict__ w1, const float* __restrict__ w2,
    unsigned short* __restrict__ Bm1, unsigned short* __restrict__ Bm2)
{
    int idx = blockIdx.x * 256 + threadIdx.x;
    if (idx < 16*BSTRIDE) {
        int o = idx / BSTRIDE, k = idx % BSTRIDE;
        int tau = k >> 4, i = k & 15;
        float v = (k < 448 && tau < 27 && i < 12) ? w1[tau*192 + i*16 + o] : 0.0f;
        Bm1[idx] = f2bf(v);
    }
    int j = idx - 16*BSTRIDE;
    if (j >= 0 && j < 32*BSTRIDE) {
        int o = j / BSTRIDE, k = j % BSTRIDE;
        int tau = k >> 4;
        int i = k & 15;
        float v = (k < 448 && tau < 27) ? w2[tau*512 + i*32 + o] : 0.0f;
        Bm2[j] = f2bf(v);
    }
}

// ---- fused bonds staging: load spin halo (issue-early) ----
__device__ __forceinline__ void bonds_load(
    const int* __restrict__ lx, int W0, int H0, int D0, int tid,
    int4* sv, int* n1, int* n2, int* n3)
{
    #pragma unroll
    for (int i = 0; i < 3; ++i) {
        int t = tid + i*256;
        if (t < 648) {
            int dd = t / 108, rem = t - dd*108;      // 108 = 6*18
            int hh = rem / 18, ww = rem - hh*18;
            int gd = wrapc(D0 + dd - 1);
            int gh = wrapc(H0 + hh - 1);
            int gw = wrapc(W0 + ww - 1);
            int gdm = (gd == 0) ? L-1 : gd-1;
            int ghm = (gh == 0) ? L-1 : gh-1;
            int gwm = (gw == 0) ? L-1 : gw-1;
            sv[i] = *reinterpret_cast<const int4*>(lx + 4*((gd*L + gh)*L + gw));
            n1[i] = lx[4*((gdm*L + gh)*L + gw) + 1];
            n2[i] = lx[4*((gd*L + ghm)*L + gw) + 2];
            n3[i] = lx[4*((gd*L + gh)*L + gwm) + 3];
        }
    }
}

// ---- fused bonds staging: dot products + ds_write (write-late), 48B slots ----
__device__ __forceinline__ void bonds_write(
    unsigned short* __restrict__ tile, int tid,
    float d00, float d01, float d11,
    const int4* sv, const int* n1, const int* n2, const int* n3)
{
    #pragma unroll
    for (int i = 0; i < 3; ++i) {
        int t = tid + i*256;
        if (t < 648) {
            int s0 = sv[i].x, s1 = sv[i].y, s2 = sv[i].z, s3 = sv[i].w;
            int r1 = n1[i], r2 = n2[i], r3 = n3[i];
            auto dot = [&](int a, int b) -> float {
                return (a == b) ? (a ? d11 : d00) : d01;
            };
            union { unsigned short s[16]; int4 q[2]; } u;
            u.s[0]  = f2bf(dot(s0, s1));
            u.s[1]  = f2bf(dot(s0, s2));
            u.s[2]  = f2bf(dot(s0, s3));
            u.s[3]  = f2bf(dot(s0, r1));
            u.s[4]  = f2bf(dot(s0, r2));
            u.s[5]  = f2bf(dot(s0, r3));
            u.s[6]  = f2bf(dot(s1, s2));
            u.s[7]  = f2bf(dot(s2, s3));
            u.s[8]  = f2bf(dot(s3, s1));
            u.s[9]  = f2bf(dot(r1, r2));
            u.s[10] = f2bf(dot(r2, r3));
            u.s[11] = f2bf(dot(r3, r1));
            u.s[12] = 0; u.s[13] = 0; u.s[14] = 0; u.s[15] = 0;
            int4* dst = reinterpret_cast<int4*>(tile + t*VSLOT);
            dst[0] = u.q[0];
            dst[1] = u.q[1];
        }
    }
}

// ---- stage 6x6x18 PADDED tile (y1 stored with 24-short voxel slots, so a
// ---- LINEAR global_load_lds copy lands the padded layout for free) ----
__device__ __forceinline__ void stage_tile24(
    const unsigned short* __restrict__ x, unsigned short* __restrict__ tile,
    int W0, int H0, int D0, int tid)
{
    #pragma unroll
    for (int i = 0; i < 8; ++i) {
        int t = tid + i*256;                     // 1944 granules of 16 B
        if (i < 7 || t < 1944) {
            int v = t / 3, p = t - v*3;          // voxel, 16B-part
            int r = v / 18, ww = v - r*18;       // r = dd*6+hh
            int dd = r / 6, hh = r - dd*6;
            int gd = wrapc(D0 + dd - 1);
            int gh = wrapc(H0 + hh - 1);
            int gw = wrapc(W0 + ww - 1);
            size_t gi = ((size_t)((gd*L + gh)*L + gw))*VSLOT + p*8;
            __builtin_amdgcn_global_load_lds(
                (const __attribute__((address_space(1))) unsigned int*)(x + gi),
                (__attribute__((address_space(3))) unsigned int*)(tile + t*8),
                16, 0, 0);
        }
    }
}

// XCD-aware bijective swizzle: 864 blocks = 8 XCDs x 108 contiguous tiles.
__device__ __forceinline__ void tile_coords(int& bid, int& W0, int& H0, int& Dz)
{
    bid = (blockIdx.z * 24 + blockIdx.y) * 6 + blockIdx.x;   // 0..863
    int nb = (bid & 7) * 108 + (bid >> 3);                   // bijective (864%8==0)
    W0 = (nb % 6) * 16;
    int t1 = nb / 6;
    H0 = (t1 % 24) * 4;
    Dz = t1 / 24;                                            // 0..5 -> D base Dz*16
}

// ---- conv1: fused bonds + 16ch (12 live) -> 16ch, B in regs, dbuf overlap,
// ---- depth-1 A-prefetch + setprio (restored from measured-60us R3 form) ----
__global__ __launch_bounds__(256, 2) void conv1_kernel(
    const int* __restrict__ lx, const float* __restrict__ tet,
    const unsigned short* __restrict__ Bm,
    const float* __restrict__ bias, unsigned short* __restrict__ y)
{
    __shared__ __attribute__((aligned(16))) unsigned short tile[2][6*6*18*VSLOT]; // 2x31104 B
    int tid = threadIdx.x;
    int bid, W0, H0, Dz;
    tile_coords(bid, W0, H0, Dz);

    int lane = tid & 63, wave = tid >> 6;
    int laneV = lane & 15, g = lane >> 4;
    int gb = g >> 1;
    int abase = laneV*VSLOT + (g & 1)*8;

    float t00 = tet[0], t01 = tet[1], t10 = tet[2], t11 = tet[3];
    float d00 = t00*t00 + t01*t01;
    float d01 = t00*t10 + t01*t11;
    float d11 = t10*t10 + t11*t11;

    // B in registers: lane's row = out-ch laneV, k-slice g*8 (wave-invariant)
    short8 bR[14];
    #pragma unroll
    for (int kt = 0; kt < 14; ++kt)
        bR[kt] = *reinterpret_cast<const short8*>(&Bm[laneV*BSTRIDE + kt*32 + g*8]);

    int4 sv[3]; int n1[3], n2[3], n3[3];
    bonds_load(lx, W0, H0, Dz*16, tid, sv, n1, n2, n3);
    bonds_write(tile[0], tid, d00, d01, d11, sv, n1, n2, n3);
    __syncthreads();

    // swapped MFMA: D[out_ch][vox] -> lane holds ch g*4+r of voxel laneV
    float bch[4];
    #pragma unroll
    for (int r = 0; r < 4; ++r) bch[r] = bias[g*4 + r];

    int moff[4];
    #pragma unroll
    for (int m = 0; m < 4; ++m) {
        int mt = wave*4 + m;                      // dd = mt>>2, hh = mt&3
        moff[m] = ((mt >> 2)*6 + (mt & 3))*ROWSTRIDE;
    }

    for (int t = 0; t < NT; ++t) {
        // issue next tile's spin gather; latency hides under this tile's MFMAs
        if (t < NT-1)
            bonds_load(lx, W0, H0, Dz*16 + 4*(t+1), tid, sv, n1, n2, n3);

        const unsigned short* tl = tile[t & 1];

        floatx4 acc[4];
        #pragma unroll
        for (int m = 0; m < 4; ++m) acc[m] = (floatx4)(0.0f);

        short8 aC[4], aN[4];
        {
            int a0 = abase + (gb ? TAU48[1] : TAU48[0]);
            #pragma unroll
            for (int m = 0; m < 4; ++m)
                aC[m] = *reinterpret_cast<const short8*>(&tl[moff[m] + a0]);
        }

        #pragma unroll
        for (int kt = 0; kt < 14; ++kt) {
            if (kt < 13) {
                int te = TAU48[2*(kt+1)];
                int to = TAU48[(2*(kt+1)+1 > 26) ? 26 : 2*(kt+1)+1];
                int an = abase + (gb ? to : te);
                #pragma unroll
                for (int m = 0; m < 4; ++m)
                    aN[m] = *reinterpret_cast<const short8*>(&tl[moff[m] + an]);
            }
            __builtin_amdgcn_s_setprio(1);
            #pragma unroll
            for (int m = 0; m < 4; ++m)
                acc[m] = __builtin_amdgcn_mfma_f32_16x16x32_bf16(bR[kt], aC[m], acc[m], 0, 0, 0);
            __builtin_amdgcn_s_setprio(0);
            if (kt < 13) {
                #pragma unroll
                for (int m = 0; m < 4; ++m) aC[m] = aN[m];
            }
        }

        // convert + ds_write next tile into the other buffer
        if (t < NT-1)
            bonds_write(tile[(t+1) & 1], tid, d00, d01, d11, sv, n1, n2, n3);

        int D0 = Dz*16 + t*4;
        #pragma unroll
        for (int m = 0; m < 4; ++m) {
            int mt = wave*4 + m;
            int d = D0 + (mt >> 2), h = H0 + (mt & 3);
            int w = W0 + laneV;
            union { unsigned short s[4]; uint2 v; } o;
            #pragma unroll
            for (int r = 0; r < 4; ++r)
                o.s[r] = f2bf(eluf(acc[m][r] + bch[r]));
            *reinterpret_cast<uint2*>(&y[((size_t)((d*L + h)*L + w))*VSLOT + g*4]) = o.v;
        }

        if (t < NT-1)
            lgkm_barrier();   // LDS visibility only; stores/gathers stay in flight
    }
}

// ---- conv2: 16 -> 32, padded dbuf LDS staging, B in regs, depth-1 A-prefetch,
// ---- setprio, fused reduce ----
__global__ __launch_bounds__(256, 2) void conv2_kernel(
    const unsigned short* __restrict__ x, const unsigned short* __restrict__ Bm,
    const float* __restrict__ bias, const float* __restrict__ wd,
    float* __restrict__ partials)
{
    __shared__ __attribute__((aligned(16))) unsigned short tile[2][6*6*18*VSLOT]; // 2x31104 B
    __shared__ float red[4];
    int tid = threadIdx.x;
    int bid, W0, H0, Dz;
    tile_coords(bid, W0, H0, Dz);

    int lane = tid & 63, wave = tid >> 6;
    int laneV = lane & 15, g = lane >> 4;
    int gb = g >> 1;
    int abase = laneV*VSLOT + (g & 1)*8;

    stage_tile24(x, tile[0], W0, H0, Dz*16, tid);

    // B in registers: rows laneV and 16+laneV (wave-invariant pattern)
    short8 bR0[14], bR1[14];
    #pragma unroll
    for (int kt = 0; kt < 14; ++kt) {
        bR0[kt] = *reinterpret_cast<const short8*>(&Bm[laneV*BSTRIDE + kt*32 + g*8]);
        bR1[kt] = *reinterpret_cast<const short8*>(&Bm[(16 + laneV)*BSTRIDE + kt*32 + g*8]);
    }

    float b2a = bias[laneV], b2b = bias[16 + laneV];
    float wda = wd[laneV],  wdb = wd[16 + laneV];

    int moff[4];
    #pragma unroll
    for (int m = 0; m < 4; ++m) {
        int mt = wave*4 + m;
        moff[m] = ((mt >> 2)*6 + (mt & 3))*ROWSTRIDE;
    }

    __syncthreads();   // tile0 DMA + B reg loads complete

    float s = 0.0f;

    for (int t = 0; t < NT; ++t) {
        if (t < NT-1)
            stage_tile24(x, tile[(t+1) & 1], W0, H0, Dz*16 + 4*(t+1), tid);

        const unsigned short* tl = tile[t & 1];

        floatx4 acc[4][2];
        #pragma unroll
        for (int m = 0; m < 4; ++m) {
            acc[m][0] = (floatx4)(0.0f);
            acc[m][1] = (floatx4)(0.0f);
        }

        short8 aC[4], aN[4];
        {
            int a0 = abase + (gb ? TAU48[1] : TAU48[0]);
            #pragma unroll
            for (int m = 0; m < 4; ++m)
                aC[m] = *reinterpret_cast<const short8*>(&tl[moff[m] + a0]);
        }

        #pragma unroll
        for (int kt = 0; kt < 14; ++kt) {
            if (kt < 13) {
                int te = TAU48[2*(kt+1)];
                int to = TAU48[(2*(kt+1)+1 > 26) ? 26 : 2*(kt+1)+1];
                int an = abase + (gb ? to : te);
                #pragma unroll
                for (int m = 0; m < 4; ++m)
                    aN[m] = *reinterpret_cast<const short8*>(&tl[moff[m] + an]);
            }
            __builtin_amdgcn_s_setprio(1);
            #pragma unroll
            for (int m = 0; m < 4; ++m) {
                acc[m][0] = __builtin_amdgcn_mfma_f32_16x16x32_bf16(aC[m], bR0[kt], acc[m][0], 0, 0, 0);
                acc[m][1] = __builtin_amdgcn_mfma_f32_16x16x32_bf16(aC[m], bR1[kt], acc[m][1], 0, 0, 0);
            }
            __builtin_amdgcn_s_setprio(0);
            if (kt < 13) {
                #pragma unroll
                for (int m = 0; m < 4; ++m) aC[m] = aN[m];
            }
        }

        #pragma unroll
        for (int m = 0; m < 4; ++m) {
            #pragma unroll
            for (int reg = 0; reg < 4; ++reg) {
                s += eluf(acc[m][0][reg] + b2a) * wda;
                s += eluf(acc[m][1][reg] + b2b) * wdb;
            }
        }

        if (t < NT-1)
            vm_barrier();    // next tile DMA complete + all reads of cur done
    }

    #pragma unroll
    for (int off = 32; off; off >>= 1) s += __shfl_down(s, off);
    if (lane == 0) red[wave] = s;
    __syncthreads();
    if (tid == 0) {
        partials[bid] = red[0] + red[1] + red[2] + red[3];
    }
}

// ---- final reduce ----
__global__ __launch_bounds__(256) void final_kernel(
    const float* __restrict__ partials, float* __restrict__ out)
{
    float s = 0.0f;
    for (int i = threadIdx.x; i < NCONV; i += 256) s += partials[i];
    #pragma unroll
    for (int off = 32; off; off >>= 1) s += __shfl_down(s, off);
    __shared__ float red[4];
    int lane = threadIdx.x & 63;
    int wv   = threadIdx.x >> 6;
    if (lane == 0) red[wv] = s;
    __syncthreads();
    if (threadIdx.x == 0)
        out[0] = (red[0] + red[1] + red[2] + red[3]) * (1.0f / (float)L3);
}

extern "C" void kernel_launch(void* const* d_in, const int* in_sizes, int n_in,
                              void* d_out, int out_size, void* d_ws, size_t ws_size,
                              hipStream_t stream) {
    const int*   lx  = (const int*)  d_in[0];
    const float* tet = (const float*)d_in[1];
    const float* w1  = (const float*)d_in[2];
    const float* b1  = (const float*)d_in[3];
    const float* w2  = (const float*)d_in[4];
    const float* b2  = (const float*)d_in[5];
    const float* wd  = (const float*)d_in[6];
    float* out = (float*)d_out;

    char* ws = (char*)d_ws;
    const size_t Y1_BYTES = (size_t)L3 * VSLOT * 2;          // 42.5 MB padded
    unsigned short* y1   = (unsigned short*)ws;
    unsigned short* Bm1  = (unsigned short*)(ws + Y1_BYTES);
    unsigned short* Bm2  = (unsigned short*)(ws + Y1_BYTES + 16*BSTRIDE*2);
    float* partials      = (float*)         (ws + Y1_BYTES + 48*BSTRIDE*2);

    prepw_kernel<<<86, 256, 0, stream>>>(w1, w2, Bm1, Bm2);
    conv1_kernel<<<dim3(6,24,6), 256, 0, stream>>>(lx, tet, Bm1, b1, y1);
    conv2_kernel<<<dim3(6,24,6), 256, 0, stream>>>(y1, Bm2, b2, wd, partials);
    final_kernel<<<1, 256, 0, stream>>>(partials, out);
}